// Round 5
// baseline (150.049 us; speedup 1.0000x reference)
//
#include <hip/hip_runtime.h>
#include <hip/hip_bf16.h>

#define N 4096
#define F 256
#define P 5
#define EPSV 1e-8f
#define NSTEP 8          // K-steps of 32 over F=256

typedef __attribute__((ext_vector_type(8))) short bf16x8;
typedef __attribute__((ext_vector_type(4))) float f32x4;

__device__ __forceinline__ f32x4 mfma16(bf16x8 a, bf16x8 b, f32x4 c) {
    return __builtin_amdgcn_mfma_f32_16x16x32_bf16(a, b, c, 0, 0, 0);
}

// K0 (fused): msg = E @ A via sparse index compaction, norms, bf16 casts,
// per-(persona,row) float4 table {alpha, beta, p, p+delta}, per-persona consts.
__global__ __launch_bounds__(256, 8) void prep_kernel(
    const float* __restrict__ E, const float* __restrict__ A,
    const float* __restrict__ persona,
    const float* __restrict__ Tt, const float* __restrict__ ee,
    const float* __restrict__ rr, const float* __restrict__ Ww,
    const int* __restrict__ times,
    __hip_bfloat16* __restrict__ Abf, __hip_bfloat16* __restrict__ Mbf,
    float4* __restrict__ qtab, float* __restrict__ cst) {
    __shared__ int cnt;
    __shared__ int list[1024];
    const int a = blockIdx.x;
    const int t = threadIdx.x;
    if (t == 0) cnt = 0;
    __syncthreads();
    const float4* erow = (const float4*)(E + (size_t)a * N);
    for (int b = t; b < N / 4; b += 256) {
        const float4 v = erow[b];
        if (v.x != 0.f) list[atomicAdd(&cnt, 1)] = 4 * b;
        if (v.y != 0.f) list[atomicAdd(&cnt, 1)] = 4 * b + 1;
        if (v.z != 0.f) list[atomicAdd(&cnt, 1)] = 4 * b + 2;
        if (v.w != 0.f) list[atomicAdd(&cnt, 1)] = 4 * b + 3;
    }
    __syncthreads();
    const int c = cnt;
    float s0 = 0.f, s1 = 0.f, s2 = 0.f, s3 = 0.f;
    int j = 0;
    for (; j + 4 <= c; j += 4) {
        s0 += A[(size_t)list[j] * F + t];
        s1 += A[(size_t)list[j + 1] * F + t];
        s2 += A[(size_t)list[j + 2] * F + t];
        s3 += A[(size_t)list[j + 3] * F + t];
    }
    for (; j < c; ++j) s0 += A[(size_t)list[j] * F + t];
    const float mv = (s0 + s1) + (s2 + s3);
    const float av = A[(size_t)a * F + t];
    Abf[(size_t)a * F + t] = __float2bfloat16(av);
    Mbf[(size_t)a * F + t] = __float2bfloat16(mv);

    float paa = av * av, pam = av * mv, pmm = mv * mv;
    #pragma unroll
    for (int o = 32; o > 0; o >>= 1) {
        paa += __shfl_down(paa, o);
        pam += __shfl_down(pam, o);
        pmm += __shfl_down(pmm, o);
    }
    __shared__ float s[3][4];
    const int wid = t >> 6;
    if ((t & 63) == 0) { s[0][wid] = paa; s[1][wid] = pam; s[2][wid] = pmm; }
    __syncthreads();
    if (t < P) {
        const float naa = s[0][0] + s[0][1] + s[0][2] + s[0][3];
        const float nam = s[1][0] + s[1][1] + s[1][2] + s[1][3];
        const float nmm = s[2][0] + s[2][1] + s[2][2] + s[2][3];
        const float Ti = Tt[t], ei = ee[t], ri = rr[t], Wi = Ww[t];
        const float wb = (1.f - ri) * Wi;
        const float n2 = ri * ri * naa + 2.f * ri * wb * nam + wb * wb * nmm;
        const float rn = rsqrtf(n2);
        const float p = persona[(size_t)(*times) * (size_t)N * P + (size_t)a * P + t];
        float4 q;
        q.x = ri * rn;                       // alpha
        q.y = wb * rn;                       // beta
        q.z = p;                             // p0
        q.w = p + (t == 0 ? 1.f : 0.f);      // p1 (i==0 init term)
        qtab[t * N + a] = q;
        if (a == 0) {
            const float invT = 1.f / (Ti + EPSV);
            const float sc = ei / (ei * __expf(invT) + EPSV);
            cst[2 * t] = invT * 1.4426950408889634f;   // k1 (log2 exponent scale)
            cst[2 * t + 1] = __log2f(sc);              // lsc (folded post-scale)
        }
    }
}

// K1: independent-wave fused 4-Gram + persona epilogue over the upper triangle.
// Each wave owns one 32x32 tile. No LDS, no barriers: fragments stream from L2
// (operands are 4MB, fully L2-resident), double-buffered in registers.
__global__ __launch_bounds__(256) void gram_kernel(
    const __hip_bfloat16* __restrict__ Abf, const __hip_bfloat16* __restrict__ Mbf,
    const float4* __restrict__ qtab, const float* __restrict__ cst,
    float* __restrict__ out) {
    const int t = threadIdx.x;
    const int lane = t & 63;
    const int w = t >> 6;

    // triangle decode over 128 tile-rows: gid -> (by <= bx)
    int gid = blockIdx.x * 4 + w;
    int bx = (int)((sqrtf(8.f * (float)gid + 1.f) - 1.f) * 0.5f);
    while ((bx + 1) * (bx + 2) / 2 <= gid) ++bx;
    while (bx * (bx + 1) / 2 > gid) --bx;
    const int by = gid - bx * (bx + 1) / 2;
    const int row0 = by << 5, col0 = bx << 5;

    const int f = lane & 15;
    const int fg = lane >> 4;          // 0..3 (k-chunk group)

    // fragment base pointers: per lane 16B at (row)*F + fg*8, k-step adds 32
    const __hip_bfloat16* pr = Abf + (size_t)(row0 + f) * F + fg * 8;
    const __hip_bfloat16* pc = Abf + (size_t)(col0 + f) * F + fg * 8;
    const size_t moff = (size_t)(Mbf - Abf);  // same layout

    f32x4 acc[4][2][2];  // [gram AA,AM,MA,MM][m][n]
    #pragma unroll
    for (int g = 0; g < 4; ++g)
        #pragma unroll
        for (int m = 0; m < 2; ++m)
            #pragma unroll
            for (int n = 0; n < 2; ++n) acc[g][m][n] = (f32x4){0.f, 0.f, 0.f, 0.f};

    // [buf][ {A m=0, A m=1, M m=0, M m=1} ]
    bf16x8 ra[2][4], rc[2][4];
    #pragma unroll
    for (int m = 0; m < 2; ++m) {
        ra[0][m]     = *(const bf16x8*)(pr + m * 16 * F);
        ra[0][2 + m] = *(const bf16x8*)(pr + moff + m * 16 * F);
        rc[0][m]     = *(const bf16x8*)(pc + m * 16 * F);
        rc[0][2 + m] = *(const bf16x8*)(pc + moff + m * 16 * F);
    }

    #pragma unroll
    for (int s = 0; s < NSTEP; ++s) {
        const int cb = s & 1, nb = cb ^ 1;
        if (s + 1 < NSTEP) {
            const int ko = (s + 1) * 32;
            #pragma unroll
            for (int m = 0; m < 2; ++m) {
                ra[nb][m]     = *(const bf16x8*)(pr + ko + m * 16 * F);
                ra[nb][2 + m] = *(const bf16x8*)(pr + moff + ko + m * 16 * F);
                rc[nb][m]     = *(const bf16x8*)(pc + ko + m * 16 * F);
                rc[nb][2 + m] = *(const bf16x8*)(pc + moff + ko + m * 16 * F);
            }
        }
        #pragma unroll
        for (int m = 0; m < 2; ++m)
            #pragma unroll
            for (int n = 0; n < 2; ++n) {
                acc[0][m][n] = mfma16(ra[cb][m],     rc[cb][n],     acc[0][m][n]);
                acc[1][m][n] = mfma16(ra[cb][m],     rc[cb][2 + n], acc[1][m][n]);
                acc[2][m][n] = mfma16(ra[cb][2 + m], rc[cb][n],     acc[2][m][n]);
                acc[3][m][n] = mfma16(ra[cb][2 + m], rc[cb][2 + n], acc[3][m][n]);
            }
    }

    // Epilogue: g symmetric; out(r,c) = sum_i th*pc0*pr1, out(c,r) = sum_i th*pr0*pc1
    const int jr = fg << 2;
    float o1[2][2][4], o2[2][2][4];
    #pragma unroll
    for (int m = 0; m < 2; ++m)
        #pragma unroll
        for (int n = 0; n < 2; ++n)
            #pragma unroll
            for (int j = 0; j < 4; ++j) { o1[m][n][j] = 0.f; o2[m][n][j] = 0.f; }

    #pragma unroll
    for (int i = 0; i < P; ++i) {
        const float k1 = cst[2 * i], lsc = cst[2 * i + 1];
        float4 qc[2];
        #pragma unroll
        for (int n = 0; n < 2; ++n)
            qc[n] = qtab[i * N + col0 + n * 16 + f];
        #pragma unroll
        for (int m = 0; m < 2; ++m) {
            #pragma unroll
            for (int j = 0; j < 4; ++j) {
                const float4 qr = qtab[i * N + row0 + m * 16 + jr + j];
                #pragma unroll
                for (int n = 0; n < 2; ++n) {
                    const float h0 = qr.x * acc[0][m][n][j] + qr.y * acc[2][m][n][j];
                    const float h1 = qr.x * acc[1][m][n][j] + qr.y * acc[3][m][n][j];
                    const float g = h0 * qc[n].x + h1 * qc[n].y;
                    const float x = exp2f(fmaf(g, k1, lsc));
                    const float e2 = exp2f(x * 2.8853900817779268f);  // exp(2x)
                    const float th = 1.f - 2.f * __builtin_amdgcn_rcpf(e2 + 1.f);
                    o1[m][n][j] = fmaf(th * qc[n].z, qr.w, o1[m][n][j]);
                    o2[m][n][j] = fmaf(th * qr.z, qc[n].w, o2[m][n][j]);
                }
            }
        }
    }

    // tile1 (row0, col0): per-element stores, lanes f give 64B-coalesced rows
    #pragma unroll
    for (int m = 0; m < 2; ++m)
        #pragma unroll
        for (int j = 0; j < 4; ++j) {
            const int gr = row0 + m * 16 + jr + j;
            #pragma unroll
            for (int n = 0; n < 2; ++n) {
                const int gc = col0 + n * 16 + f;
                out[(size_t)gr * N + gc] = o1[m][n][j];
            }
        }

    // tile2 (col0, row0): direct transposed scalar stores; the 4 fg-lanes plus the
    // j-unroll fill full 64B sectors per output row -> L2 write-merges them.
    if (by != bx) {
        #pragma unroll
        for (int m = 0; m < 2; ++m)
            #pragma unroll
            for (int j = 0; j < 4; ++j) {
                const int gr = row0 + m * 16 + jr + j;
                #pragma unroll
                for (int n = 0; n < 2; ++n) {
                    const int gc = col0 + n * 16 + f;
                    out[(size_t)gc * N + gr] = o2[m][n][j];
                }
            }
    }
}

extern "C" void kernel_launch(void* const* d_in, const int* in_sizes, int n_in,
                              void* d_out, int out_size, void* d_ws, size_t ws_size,
                              hipStream_t stream) {
    const float* A = (const float*)d_in[0];
    const float* E = (const float*)d_in[1];
    const float* persona = (const float*)d_in[2];
    const float* T = (const float*)d_in[3];
    const float* e = (const float*)d_in[4];
    const float* r = (const float*)d_in[5];
    const float* W = (const float*)d_in[6];
    const int* times = (const int*)d_in[7];
    float* out = (float*)d_out;

    char* ws = (char*)d_ws;
    __hip_bfloat16* Abf = (__hip_bfloat16*)ws;                    // 2 MB
    __hip_bfloat16* Mbf = (__hip_bfloat16*)(ws + (2 << 20));      // 2 MB
    float4* qtab = (float4*)(ws + (4 << 20));                     // 320 KB
    float* cst = (float*)(ws + (4 << 20) + P * N * 16);           // 40 B

    prep_kernel<<<N, 256, 0, stream>>>(E, A, persona, T, e, r, W, times,
                                       Abf, Mbf, qtab, cst);
    const int ntri = 128 * 129 / 2;  // 8256 32x32 upper-triangle tiles
    gram_kernel<<<(ntri + 3) / 4, 256, 0, stream>>>(Abf, Mbf, qtab, cst, out);
}

// Round 6
// 129.190 us; speedup vs baseline: 1.1615x; 1.1615x over previous
//
#include <hip/hip_runtime.h>
#include <hip/hip_bf16.h>

#define N 4096
#define F 256
#define P 5
#define EPSV 1e-8f
#define NSTEP 8          // K-steps of 32 over F=256
#define NBUF 3           // 3-deep LDS pipeline, 16KB per buffer

typedef __attribute__((ext_vector_type(8))) short bf16x8;
typedef __attribute__((ext_vector_type(4))) float f32x4;

__device__ __forceinline__ f32x4 mfma16(bf16x8 a, bf16x8 b, f32x4 c) {
    return __builtin_amdgcn_mfma_f32_16x16x32_bf16(a, b, c, 0, 0, 0);
}

__device__ __forceinline__ void gload16(const __hip_bfloat16* src, const char* ldsdst) {
    __builtin_amdgcn_global_load_lds(
        (const __attribute__((address_space(1))) void*)src,
        (__attribute__((address_space(3))) void*)ldsdst, 16, 0, 0);
}

// K0 (fused): msg = E @ A via sparse index compaction, norms, bf16 casts,
// per-(persona,row) float4 table {alpha, beta, p, p+delta}, per-persona consts.
__global__ __launch_bounds__(256, 8) void prep_kernel(
    const float* __restrict__ E, const float* __restrict__ A,
    const float* __restrict__ persona,
    const float* __restrict__ Tt, const float* __restrict__ ee,
    const float* __restrict__ rr, const float* __restrict__ Ww,
    const int* __restrict__ times,
    __hip_bfloat16* __restrict__ Abf, __hip_bfloat16* __restrict__ Mbf,
    float4* __restrict__ qtab, float* __restrict__ cst) {
    __shared__ int cnt;
    __shared__ int list[1024];
    const int a = blockIdx.x;
    const int t = threadIdx.x;
    if (t == 0) cnt = 0;
    __syncthreads();
    const float4* erow = (const float4*)(E + (size_t)a * N);
    for (int b = t; b < N / 4; b += 256) {
        const float4 v = erow[b];
        if (v.x != 0.f) list[atomicAdd(&cnt, 1)] = 4 * b;
        if (v.y != 0.f) list[atomicAdd(&cnt, 1)] = 4 * b + 1;
        if (v.z != 0.f) list[atomicAdd(&cnt, 1)] = 4 * b + 2;
        if (v.w != 0.f) list[atomicAdd(&cnt, 1)] = 4 * b + 3;
    }
    __syncthreads();
    const int c = cnt;
    float s0 = 0.f, s1 = 0.f, s2 = 0.f, s3 = 0.f;
    int j = 0;
    for (; j + 4 <= c; j += 4) {
        s0 += A[(size_t)list[j] * F + t];
        s1 += A[(size_t)list[j + 1] * F + t];
        s2 += A[(size_t)list[j + 2] * F + t];
        s3 += A[(size_t)list[j + 3] * F + t];
    }
    for (; j < c; ++j) s0 += A[(size_t)list[j] * F + t];
    const float mv = (s0 + s1) + (s2 + s3);
    const float av = A[(size_t)a * F + t];
    Abf[(size_t)a * F + t] = __float2bfloat16(av);
    Mbf[(size_t)a * F + t] = __float2bfloat16(mv);

    float paa = av * av, pam = av * mv, pmm = mv * mv;
    #pragma unroll
    for (int o = 32; o > 0; o >>= 1) {
        paa += __shfl_down(paa, o);
        pam += __shfl_down(pam, o);
        pmm += __shfl_down(pmm, o);
    }
    __shared__ float s[3][4];
    const int wid = t >> 6;
    if ((t & 63) == 0) { s[0][wid] = paa; s[1][wid] = pam; s[2][wid] = pmm; }
    __syncthreads();
    if (t < P) {
        const float naa = s[0][0] + s[0][1] + s[0][2] + s[0][3];
        const float nam = s[1][0] + s[1][1] + s[1][2] + s[1][3];
        const float nmm = s[2][0] + s[2][1] + s[2][2] + s[2][3];
        const float Ti = Tt[t], ei = ee[t], ri = rr[t], Wi = Ww[t];
        const float wb = (1.f - ri) * Wi;
        const float n2 = ri * ri * naa + 2.f * ri * wb * nam + wb * wb * nmm;
        const float rn = rsqrtf(n2);
        const float p = persona[(size_t)(*times) * (size_t)N * P + (size_t)a * P + t];
        float4 q;
        q.x = ri * rn;                       // alpha
        q.y = wb * rn;                       // beta
        q.z = p;                             // p0
        q.w = p + (t == 0 ? 1.f : 0.f);      // p1 (i==0 init term)
        qtab[t * N + a] = q;
        if (a == 0) {
            const float invT = 1.f / (Ti + EPSV);
            const float sc = ei / (ei * __expf(invT) + EPSV);
            cst[2 * t] = invT * 1.4426950408889634f;   // k1 (log2 exponent scale)
            cst[2 * t + 1] = __log2f(sc);              // lsc (folded post-scale)
        }
    }
}

// K1: fused 4-Gram MFMA + dual-tile persona epilogue over the upper triangle.
// 64x64 tile, 4 waves (2x2). 3-buffer LDS pipeline with counted vmcnt + raw
// barriers (no vmcnt(0) drains in the main loop).
__global__ __launch_bounds__(256) void gram_kernel(
    const __hip_bfloat16* __restrict__ Abf, const __hip_bfloat16* __restrict__ Mbf,
    const float4* __restrict__ qtab, const float* __restrict__ cst,
    float* __restrict__ out) {
    // NBUF buffers x 4 panels (rowA,rowM,colA,colM) x [64][32] bf16 (4KB each).
    __shared__ __align__(16) char smem[NBUF * 16384];

    const int t = threadIdx.x;
    const int lane = t & 63;
    const int w = t >> 6;
    const int wr = w >> 1, wc = w & 1;

    // triangle decode: bid -> (by <= bx)
    int bid = blockIdx.x;
    int bx = (int)((sqrtf(8.f * (float)bid + 1.f) - 1.f) * 0.5f);
    while ((bx + 1) * (bx + 2) / 2 <= bid) ++bx;
    while (bx * (bx + 1) / 2 > bid) --bx;
    const int by = bid - bx * (bx + 1) / 2;
    const int row0 = by << 6, col0 = bx << 6;

    // staging: wave w stages rows [w*16, w*16+16) of each panel, 16B/lane,
    // source column pre-swizzled (involution slot^((row>>1)&3)); LDS linear.
    const int srow = lane >> 2;
    const int sslot = (lane & 3) ^ ((srow >> 1) & 3);
    const size_t rbase = (size_t)row0 * F;
    const size_t cbase = (size_t)col0 * F;
    const size_t soff = (size_t)(w * 16 + srow) * F + (sslot << 3);

    #define STAGE(b, ks)  do {                                            \
        const char* lb = smem + (b) * 16384 + w * 1024;                   \
        gload16(Abf + rbase + soff + (ks), lb);                           \
        gload16(Mbf + rbase + soff + (ks), lb + 4096);                    \
        gload16(Abf + cbase + soff + (ks), lb + 8192);                    \
        gload16(Mbf + cbase + soff + (ks), lb + 12288);                   \
    } while (0)

    const int frow = lane & 15;
    const int rdslot = ((lane >> 4) ^ ((frow >> 1) & 3)) << 4;

    f32x4 acc[4][2][2];
    #pragma unroll
    for (int g = 0; g < 4; ++g)
        #pragma unroll
        for (int m = 0; m < 2; ++m)
            #pragma unroll
            for (int n = 0; n < 2; ++n) acc[g][m][n] = (f32x4){0.f, 0.f, 0.f, 0.f};

    // prologue: stage steps 0 and 1; wait for step 0 only (vmcnt(4) leaves step 1 in flight)
    STAGE(0, 0);
    STAGE(1, 32);
    asm volatile("s_waitcnt vmcnt(4)" ::: "memory");
    __builtin_amdgcn_sched_barrier(0);
    __builtin_amdgcn_s_barrier();
    __builtin_amdgcn_sched_barrier(0);

    #pragma unroll
    for (int s = 0; s < NSTEP; ++s) {
        // stage s+2 (overwrites buffer (s-1)%3, fully consumed before the
        // bottom barrier of iteration s-1)
        if (s + 2 < NSTEP) STAGE((s + 2) % NBUF, (s + 2) * 32);

        const char* base = smem + (s % NBUF) * 16384;
        bf16x8 aA[2], aM[2], bA[2], bM[2];
        #pragma unroll
        for (int m = 0; m < 2; ++m) {
            const int ro = (wr * 32 + m * 16 + frow) * 64 + rdslot;
            aA[m] = *(const bf16x8*)(base + ro);
            aM[m] = *(const bf16x8*)(base + 4096 + ro);
        }
        #pragma unroll
        for (int n = 0; n < 2; ++n) {
            const int co = (wc * 32 + n * 16 + frow) * 64 + rdslot;
            bA[n] = *(const bf16x8*)(base + 8192 + co);
            bM[n] = *(const bf16x8*)(base + 12288 + co);
        }
        #pragma unroll
        for (int m = 0; m < 2; ++m)
            #pragma unroll
            for (int n = 0; n < 2; ++n) {
                acc[0][m][n] = mfma16(aA[m], bA[n], acc[0][m][n]);
                acc[1][m][n] = mfma16(aA[m], bM[n], acc[1][m][n]);
                acc[2][m][n] = mfma16(aM[m], bA[n], acc[2][m][n]);
                acc[3][m][n] = mfma16(aM[m], bM[n], acc[3][m][n]);
            }

        // bottom sync: step s+1's loads must have landed for ALL waves before
        // the next iteration reads them. Counted wait: only step s+2's 4 loads
        // may remain in flight (vmcnt(0) on the last staged step).
        if (s + 1 < NSTEP) {
            if (s + 2 < NSTEP) {
                asm volatile("s_waitcnt vmcnt(4)" ::: "memory");
            } else {
                asm volatile("s_waitcnt vmcnt(0)" ::: "memory");
            }
            __builtin_amdgcn_sched_barrier(0);
            __builtin_amdgcn_s_barrier();
            __builtin_amdgcn_sched_barrier(0);
        }
    }

    // Epilogue: g symmetric; out(r,c) = sum th*pc0*pr1, out(c,r) = sum th*pr0*pc1
    const int jr = (lane >> 4) << 2;
    float o1[2][2][4], o2[2][2][4];
    #pragma unroll
    for (int m = 0; m < 2; ++m)
        #pragma unroll
        for (int n = 0; n < 2; ++n)
            #pragma unroll
            for (int j = 0; j < 4; ++j) { o1[m][n][j] = 0.f; o2[m][n][j] = 0.f; }

    #pragma unroll
    for (int i = 0; i < P; ++i) {
        const float k1 = cst[2 * i], lsc = cst[2 * i + 1];
        float4 qc[2];
        #pragma unroll
        for (int n = 0; n < 2; ++n)
            qc[n] = qtab[i * N + col0 + wc * 32 + n * 16 + frow];
        #pragma unroll
        for (int m = 0; m < 2; ++m) {
            #pragma unroll
            for (int j = 0; j < 4; ++j) {
                const int gr = row0 + wr * 32 + m * 16 + jr + j;
                const float4 qr = qtab[i * N + gr];
                #pragma unroll
                for (int n = 0; n < 2; ++n) {
                    const float h0 = qr.x * acc[0][m][n][j] + qr.y * acc[2][m][n][j];
                    const float h1 = qr.x * acc[1][m][n][j] + qr.y * acc[3][m][n][j];
                    const float g = h0 * qc[n].x + h1 * qc[n].y;
                    const float x = exp2f(fmaf(g, k1, lsc));
                    const float e2 = exp2f(x * 2.8853900817779268f);  // exp(2x)
                    const float th = 1.f - 2.f * __builtin_amdgcn_rcpf(e2 + 1.f);
                    o1[m][n][j] = fmaf(th * qc[n].z, qr.w, o1[m][n][j]);
                    o2[m][n][j] = fmaf(th * qr.z, qc[n].w, o2[m][n][j]);
                }
            }
        }
    }

    // tile1 (row0, col0): direct coalesced stores
    #pragma unroll
    for (int m = 0; m < 2; ++m)
        #pragma unroll
        for (int j = 0; j < 4; ++j) {
            const int gr = row0 + wr * 32 + m * 16 + jr + j;
            #pragma unroll
            for (int n = 0; n < 2; ++n) {
                const int gc = col0 + wc * 32 + n * 16 + frow;
                out[(size_t)gr * N + gc] = o1[m][n][j];
            }
        }

    // tile2 (col0, row0): transpose through LDS (XOR-swizzled f32 [64][64] in
    // buffer 0; last reads of buffer 0 were iter 6, done before its barrier),
    // then float4 stores
    if (by != bx) {
        float* tb = (float*)smem;
        #pragma unroll
        for (int m = 0; m < 2; ++m)
            #pragma unroll
            for (int n = 0; n < 2; ++n) {
                const int lc = wc * 32 + n * 16 + frow;
                #pragma unroll
                for (int j = 0; j < 4; ++j) {
                    const int lr = wr * 32 + m * 16 + jr + j;
                    tb[lc * 64 + (lr ^ ((lc & 15) << 2))] = o2[m][n][j];
                }
            }
        __syncthreads();
        const int trow = t >> 2;
        const int tc4 = (t & 3) << 2;
        #pragma unroll
        for (int k = 0; k < 4; ++k) {
            const int col = (tc4 + k * 16) ^ ((trow & 15) << 2);
            const float4 v = *(const float4*)&tb[trow * 64 + col];
            *(float4*)&out[(size_t)(col0 + trow) * N + row0 + tc4 + k * 16] = v;
        }
    }
    #undef STAGE
}

extern "C" void kernel_launch(void* const* d_in, const int* in_sizes, int n_in,
                              void* d_out, int out_size, void* d_ws, size_t ws_size,
                              hipStream_t stream) {
    const float* A = (const float*)d_in[0];
    const float* E = (const float*)d_in[1];
    const float* persona = (const float*)d_in[2];
    const float* T = (const float*)d_in[3];
    const float* e = (const float*)d_in[4];
    const float* r = (const float*)d_in[5];
    const float* W = (const float*)d_in[6];
    const int* times = (const int*)d_in[7];
    float* out = (float*)d_out;

    char* ws = (char*)d_ws;
    __hip_bfloat16* Abf = (__hip_bfloat16*)ws;                    // 2 MB
    __hip_bfloat16* Mbf = (__hip_bfloat16*)(ws + (2 << 20));      // 2 MB
    float4* qtab = (float4*)(ws + (4 << 20));                     // 320 KB
    float* cst = (float*)(ws + (4 << 20) + P * N * 16);           // 40 B

    prep_kernel<<<N, 256, 0, stream>>>(E, A, persona, T, e, r, W, times,
                                       Abf, Mbf, qtab, cst);
    const int ntri = 64 * 65 / 2;  // 2080 upper-triangle tiles
    gram_kernel<<<ntri, 256, 0, stream>>>(Abf, Mbf, qtab, cst, out);
}

// Round 7
// 111.810 us; speedup vs baseline: 1.3420x; 1.1554x over previous
//
#include <hip/hip_runtime.h>
#include <hip/hip_bf16.h>

#define N 4096
#define F 256
#define P 5
#define EPSV 1e-8f
#define BK 32
#define NSTEP (F / BK)  // 8

typedef __attribute__((ext_vector_type(8))) short bf16x8;
typedef __attribute__((ext_vector_type(4))) float f32x4;

__device__ __forceinline__ f32x4 mfma16(bf16x8 a, bf16x8 b, f32x4 c) {
    return __builtin_amdgcn_mfma_f32_16x16x32_bf16(a, b, c, 0, 0, 0);
}

__device__ __forceinline__ void gload16(const void* src, const char* ldsdst) {
    __builtin_amdgcn_global_load_lds(
        (const __attribute__((address_space(1))) void*)src,
        (__attribute__((address_space(3))) void*)ldsdst, 16, 0, 0);
}

// K0 (fused): msg = E @ A via sparse index compaction, norms, bf16 casts,
// per-(agent,persona) float4 table {alpha, beta, p, p+delta} (AoS by agent),
// per-persona consts.
__global__ __launch_bounds__(256, 8) void prep_kernel(
    const float* __restrict__ E, const float* __restrict__ A,
    const float* __restrict__ persona,
    const float* __restrict__ Tt, const float* __restrict__ ee,
    const float* __restrict__ rr, const float* __restrict__ Ww,
    const int* __restrict__ times,
    __hip_bfloat16* __restrict__ Abf, __hip_bfloat16* __restrict__ Mbf,
    float4* __restrict__ qtab, float* __restrict__ cst) {
    __shared__ int cnt;
    __shared__ int list[1024];
    const int a = blockIdx.x;
    const int t = threadIdx.x;
    if (t == 0) cnt = 0;
    __syncthreads();
    const float4* erow = (const float4*)(E + (size_t)a * N);
    for (int b = t; b < N / 4; b += 256) {
        const float4 v = erow[b];
        if (v.x != 0.f) list[atomicAdd(&cnt, 1)] = 4 * b;
        if (v.y != 0.f) list[atomicAdd(&cnt, 1)] = 4 * b + 1;
        if (v.z != 0.f) list[atomicAdd(&cnt, 1)] = 4 * b + 2;
        if (v.w != 0.f) list[atomicAdd(&cnt, 1)] = 4 * b + 3;
    }
    __syncthreads();
    const int c = cnt;
    float s0 = 0.f, s1 = 0.f, s2 = 0.f, s3 = 0.f;
    int j = 0;
    for (; j + 4 <= c; j += 4) {
        s0 += A[(size_t)list[j] * F + t];
        s1 += A[(size_t)list[j + 1] * F + t];
        s2 += A[(size_t)list[j + 2] * F + t];
        s3 += A[(size_t)list[j + 3] * F + t];
    }
    for (; j < c; ++j) s0 += A[(size_t)list[j] * F + t];
    const float mv = (s0 + s1) + (s2 + s3);
    const float av = A[(size_t)a * F + t];
    Abf[(size_t)a * F + t] = __float2bfloat16(av);
    Mbf[(size_t)a * F + t] = __float2bfloat16(mv);

    float paa = av * av, pam = av * mv, pmm = mv * mv;
    #pragma unroll
    for (int o = 32; o > 0; o >>= 1) {
        paa += __shfl_down(paa, o);
        pam += __shfl_down(pam, o);
        pmm += __shfl_down(pmm, o);
    }
    __shared__ float s[3][4];
    const int wid = t >> 6;
    if ((t & 63) == 0) { s[0][wid] = paa; s[1][wid] = pam; s[2][wid] = pmm; }
    __syncthreads();
    if (t < P) {
        const float naa = s[0][0] + s[0][1] + s[0][2] + s[0][3];
        const float nam = s[1][0] + s[1][1] + s[1][2] + s[1][3];
        const float nmm = s[2][0] + s[2][1] + s[2][2] + s[2][3];
        const float Ti = Tt[t], ei = ee[t], ri = rr[t], Wi = Ww[t];
        const float wb = (1.f - ri) * Wi;
        const float n2 = ri * ri * naa + 2.f * ri * wb * nam + wb * wb * nmm;
        const float rn = rsqrtf(n2);
        const float p = persona[(size_t)(*times) * (size_t)N * P + (size_t)a * P + t];
        float4 q;
        q.x = ri * rn;                       // alpha
        q.y = wb * rn;                       // beta
        q.z = p;                             // p0
        q.w = p + (t == 0 ? 1.f : 0.f);      // p1 (i==0 init term)
        qtab[a * P + t] = q;                 // AoS by agent: personas contiguous
        if (a == 0) {
            const float invT = 1.f / (Ti + EPSV);
            const float sc = ei / (ei * __expf(invT) + EPSV);
            cst[2 * t] = invT * 1.4426950408889634f;   // k1 (log2 exponent scale)
            cst[2 * t + 1] = __log2f(sc);              // lsc (folded post-scale)
        }
    }
}

// K1: fused 4-Gram MFMA + dual-tile persona epilogue over the upper triangle.
// 64x64 tile, 4 waves (2x2), global_load_lds double-buffered staging, swizzled LDS.
// Block's qtab slice (row+col, 10KB) staged to LDS once for the epilogue.
__global__ __launch_bounds__(256) void gram_kernel(
    const __hip_bfloat16* __restrict__ Abf, const __hip_bfloat16* __restrict__ Mbf,
    const float4* __restrict__ qtab, const float* __restrict__ cst,
    float* __restrict__ out) {
    // [0,32768): 2 buffers x 4 panels x [64][32] bf16 (reused for transpose).
    // [32768,37888): qrow (64 agents x 5 personas x float4)
    // [37888,43008): qcol
    __shared__ __align__(16) char smem[43008];

    const int t = threadIdx.x;
    const int lane = t & 63;
    const int w = t >> 6;
    const int wr = w >> 1, wc = w & 1;

    // triangle decode: bid -> (by <= bx)
    int bid = blockIdx.x;
    int bx = (int)((sqrtf(8.f * (float)bid + 1.f) - 1.f) * 0.5f);
    while ((bx + 1) * (bx + 2) / 2 <= bid) ++bx;
    while (bx * (bx + 1) / 2 > bid) --bx;
    const int by = bid - bx * (bx + 1) / 2;
    const int row0 = by << 6, col0 = bx << 6;

    // staging: wave w stages rows [w*16, w*16+16) of each panel, 16B/lane,
    // source column pre-swizzled (involution: slot ^ ((row>>1)&3)); LDS linear.
    const int srow = lane >> 2;
    const int sslot = (lane & 3) ^ ((lane >> 3) & 3);
    const size_t rbase = (size_t)row0 * F;
    const size_t cbase = (size_t)col0 * F;
    const size_t soff = (size_t)(w * 16 + srow) * F + (sslot << 3);

    #define STAGE(b, ks)  do {                                            \
        const char* lb = smem + (b) * 16384 + w * 1024;                   \
        gload16(Abf + rbase + soff + (ks), lb);                           \
        gload16(Mbf + rbase + soff + (ks), lb + 4096);                    \
        gload16(Abf + cbase + soff + (ks), lb + 8192);                    \
        gload16(Mbf + cbase + soff + (ks), lb + 12288);                   \
    } while (0)

    const int frow = lane & 15;
    const int rdslot = ((lane >> 4) ^ ((frow >> 1) & 3)) << 4;

    f32x4 acc[4][2][2];
    #pragma unroll
    for (int g = 0; g < 4; ++g)
        #pragma unroll
        for (int m = 0; m < 2; ++m)
            #pragma unroll
            for (int n = 0; n < 2; ++n) acc[g][m][n] = (f32x4){0.f, 0.f, 0.f, 0.f};

    STAGE(0, 0);
    // qtab slice -> LDS (wave 0: row panel, wave 1: col panel), 5KB each,
    // contiguous float4 runs; consumed only at the epilogue.
    if (w == 0) {
        #pragma unroll
        for (int it = 0; it < 5; ++it)
            gload16(qtab + row0 * P + it * 64 + lane, smem + 32768 + it * 1024);
    } else if (w == 1) {
        #pragma unroll
        for (int it = 0; it < 5; ++it)
            gload16(qtab + col0 * P + it * 64 + lane, smem + 37888 + it * 1024);
    }
    __syncthreads();
    for (int s = 0; s < NSTEP; ++s) {
        const int b = s & 1;
        if (s + 1 < NSTEP) STAGE(b ^ 1, (s + 1) * BK);
        const char* base = smem + b * 16384;
        bf16x8 aA[2], aM[2], bA[2], bM[2];
        #pragma unroll
        for (int m = 0; m < 2; ++m) {
            const int ro = (wr * 32 + m * 16 + frow) * 64 + rdslot;
            aA[m] = *(const bf16x8*)(base + ro);
            aM[m] = *(const bf16x8*)(base + 4096 + ro);
        }
        #pragma unroll
        for (int n = 0; n < 2; ++n) {
            const int co = (wc * 32 + n * 16 + frow) * 64 + rdslot;
            bA[n] = *(const bf16x8*)(base + 8192 + co);
            bM[n] = *(const bf16x8*)(base + 12288 + co);
        }
        #pragma unroll
        for (int m = 0; m < 2; ++m)
            #pragma unroll
            for (int n = 0; n < 2; ++n) {
                acc[0][m][n] = mfma16(aA[m], bA[n], acc[0][m][n]);
                acc[1][m][n] = mfma16(aA[m], bM[n], acc[1][m][n]);
                acc[2][m][n] = mfma16(aM[m], bA[n], acc[2][m][n]);
                acc[3][m][n] = mfma16(aM[m], bM[n], acc[3][m][n]);
            }
        __syncthreads();
    }

    // Epilogue: g symmetric; out(r,c) = sum th*pc0*pr1, out(c,r) = sum th*pr0*pc1
    const float4* qrow = (const float4*)(smem + 32768);
    const float4* qcol = (const float4*)(smem + 37888);
    const int jr = (lane >> 4) << 2;
    float o1[2][2][4], o2[2][2][4];
    #pragma unroll
    for (int m = 0; m < 2; ++m)
        #pragma unroll
        for (int n = 0; n < 2; ++n)
            #pragma unroll
            for (int j = 0; j < 4; ++j) { o1[m][n][j] = 0.f; o2[m][n][j] = 0.f; }

    #pragma unroll
    for (int i = 0; i < P; ++i) {
        const float k1 = cst[2 * i], lsc = cst[2 * i + 1];
        float4 qc[2];
        #pragma unroll
        for (int n = 0; n < 2; ++n)
            qc[n] = qcol[(wc * 32 + n * 16 + frow) * P + i];
        #pragma unroll
        for (int m = 0; m < 2; ++m) {
            #pragma unroll
            for (int j = 0; j < 4; ++j) {
                const float4 qr = qrow[(wr * 32 + m * 16 + jr + j) * P + i];
                #pragma unroll
                for (int n = 0; n < 2; ++n) {
                    const float h0 = qr.x * acc[0][m][n][j] + qr.y * acc[2][m][n][j];
                    const float h1 = qr.x * acc[1][m][n][j] + qr.y * acc[3][m][n][j];
                    const float g = h0 * qc[n].x + h1 * qc[n].y;
                    const float x = exp2f(fmaf(g, k1, lsc));
                    const float e2 = exp2f(x * 2.8853900817779268f);  // exp(2x)
                    const float th = 1.f - 2.f * __builtin_amdgcn_rcpf(e2 + 1.f);
                    o1[m][n][j] = fmaf(th * qc[n].z, qr.w, o1[m][n][j]);
                    o2[m][n][j] = fmaf(th * qr.z, qc[n].w, o2[m][n][j]);
                }
            }
        }
    }

    // tile1 (row0, col0): direct coalesced stores
    #pragma unroll
    for (int m = 0; m < 2; ++m)
        #pragma unroll
        for (int j = 0; j < 4; ++j) {
            const int gr = row0 + wr * 32 + m * 16 + jr + j;
            #pragma unroll
            for (int n = 0; n < 2; ++n) {
                const int gc = col0 + wc * 32 + n * 16 + frow;
                out[(size_t)gr * N + gc] = o1[m][n][j];
            }
        }

    // tile2 (col0, row0): transpose through LDS (XOR-swizzled f32 [64][64] in
    // the panel area; last panel reads finished before final loop barrier),
    // then float4 stores
    if (by != bx) {
        float* tb = (float*)smem;
        #pragma unroll
        for (int m = 0; m < 2; ++m)
            #pragma unroll
            for (int n = 0; n < 2; ++n) {
                const int lc = wc * 32 + n * 16 + frow;
                #pragma unroll
                for (int j = 0; j < 4; ++j) {
                    const int lr = wr * 32 + m * 16 + jr + j;
                    tb[lc * 64 + (lr ^ ((lc & 15) << 2))] = o2[m][n][j];
                }
            }
        __syncthreads();
        const int trow = t >> 2;
        const int tc4 = (t & 3) << 2;
        #pragma unroll
        for (int k = 0; k < 4; ++k) {
            const int col = (tc4 + k * 16) ^ ((trow & 15) << 2);
            const float4 v = *(const float4*)&tb[trow * 64 + col];
            *(float4*)&out[(size_t)(col0 + trow) * N + row0 + tc4 + k * 16] = v;
        }
    }
    #undef STAGE
}

extern "C" void kernel_launch(void* const* d_in, const int* in_sizes, int n_in,
                              void* d_out, int out_size, void* d_ws, size_t ws_size,
                              hipStream_t stream) {
    const float* A = (const float*)d_in[0];
    const float* E = (const float*)d_in[1];
    const float* persona = (const float*)d_in[2];
    const float* T = (const float*)d_in[3];
    const float* e = (const float*)d_in[4];
    const float* r = (const float*)d_in[5];
    const float* W = (const float*)d_in[6];
    const int* times = (const int*)d_in[7];
    float* out = (float*)d_out;

    char* ws = (char*)d_ws;
    __hip_bfloat16* Abf = (__hip_bfloat16*)ws;                    // 2 MB
    __hip_bfloat16* Mbf = (__hip_bfloat16*)(ws + (2 << 20));      // 2 MB
    float4* qtab = (float4*)(ws + (4 << 20));                     // 320 KB
    float* cst = (float*)(ws + (4 << 20) + P * N * 16);           // 40 B

    prep_kernel<<<N, 256, 0, stream>>>(E, A, persona, T, e, r, W, times,
                                       Abf, Mbf, qtab, cst);
    const int ntri = 64 * 65 / 2;  // 2080 upper-triangle tiles
    gram_kernel<<<ntri, 256, 0, stream>>>(Abf, Mbf, qtab, cst, out);
}

// Round 8
// 104.209 us; speedup vs baseline: 1.4399x; 1.0729x over previous
//
#include <hip/hip_runtime.h>
#include <hip/hip_bf16.h>

#define N 4096
#define F 256
#define P 5
#define EPSV 1e-8f
#define BK 32
#define NSTEP (F / BK)  // 8

typedef __attribute__((ext_vector_type(8))) short bf16x8;
typedef __attribute__((ext_vector_type(4))) float f32x4;

__device__ __forceinline__ f32x4 mfma16(bf16x8 a, bf16x8 b, f32x4 c) {
    return __builtin_amdgcn_mfma_f32_16x16x32_bf16(a, b, c, 0, 0, 0);
}

__device__ __forceinline__ void gload16(const void* src, const char* ldsdst) {
    __builtin_amdgcn_global_load_lds(
        (const __attribute__((address_space(1))) void*)src,
        (__attribute__((address_space(3))) void*)ldsdst, 16, 0, 0);
}

// K0 (fused): msg = E @ A via sparse index compaction, norms, bf16 casts,
// per-(agent,persona) float4 table {alpha, beta, p, p+delta} (AoS by agent),
// per-persona consts.
__global__ __launch_bounds__(256, 8) void prep_kernel(
    const float* __restrict__ E, const float* __restrict__ A,
    const float* __restrict__ persona,
    const float* __restrict__ Tt, const float* __restrict__ ee,
    const float* __restrict__ rr, const float* __restrict__ Ww,
    const int* __restrict__ times,
    __hip_bfloat16* __restrict__ Abf, __hip_bfloat16* __restrict__ Mbf,
    float4* __restrict__ qtab, float* __restrict__ cst) {
    __shared__ int cnt;
    __shared__ int list[1024];
    const int a = blockIdx.x;
    const int t = threadIdx.x;
    if (t == 0) cnt = 0;
    __syncthreads();
    const float4* erow = (const float4*)(E + (size_t)a * N);
    for (int b = t; b < N / 4; b += 256) {
        const float4 v = erow[b];
        if (v.x != 0.f) list[atomicAdd(&cnt, 1)] = 4 * b;
        if (v.y != 0.f) list[atomicAdd(&cnt, 1)] = 4 * b + 1;
        if (v.z != 0.f) list[atomicAdd(&cnt, 1)] = 4 * b + 2;
        if (v.w != 0.f) list[atomicAdd(&cnt, 1)] = 4 * b + 3;
    }
    __syncthreads();
    const int c = cnt;
    float s0 = 0.f, s1 = 0.f, s2 = 0.f, s3 = 0.f;
    int j = 0;
    for (; j + 4 <= c; j += 4) {
        s0 += A[(size_t)list[j] * F + t];
        s1 += A[(size_t)list[j + 1] * F + t];
        s2 += A[(size_t)list[j + 2] * F + t];
        s3 += A[(size_t)list[j + 3] * F + t];
    }
    for (; j < c; ++j) s0 += A[(size_t)list[j] * F + t];
    const float mv = (s0 + s1) + (s2 + s3);
    const float av = A[(size_t)a * F + t];
    Abf[(size_t)a * F + t] = __float2bfloat16(av);
    Mbf[(size_t)a * F + t] = __float2bfloat16(mv);

    float paa = av * av, pam = av * mv, pmm = mv * mv;
    #pragma unroll
    for (int o = 32; o > 0; o >>= 1) {
        paa += __shfl_down(paa, o);
        pam += __shfl_down(pam, o);
        pmm += __shfl_down(pmm, o);
    }
    __shared__ float s[3][4];
    const int wid = t >> 6;
    if ((t & 63) == 0) { s[0][wid] = paa; s[1][wid] = pam; s[2][wid] = pmm; }
    __syncthreads();
    if (t < P) {
        const float naa = s[0][0] + s[0][1] + s[0][2] + s[0][3];
        const float nam = s[1][0] + s[1][1] + s[1][2] + s[1][3];
        const float nmm = s[2][0] + s[2][1] + s[2][2] + s[2][3];
        const float Ti = Tt[t], ei = ee[t], ri = rr[t], Wi = Ww[t];
        const float wb = (1.f - ri) * Wi;
        const float n2 = ri * ri * naa + 2.f * ri * wb * nam + wb * wb * nmm;
        const float rn = rsqrtf(n2);
        const float p = persona[(size_t)(*times) * (size_t)N * P + (size_t)a * P + t];
        float4 q;
        q.x = ri * rn;                       // alpha
        q.y = wb * rn;                       // beta
        q.z = p;                             // p0
        q.w = p + (t == 0 ? 1.f : 0.f);      // p1 (i==0 init term)
        qtab[a * P + t] = q;                 // AoS by agent: personas contiguous
        if (a == 0) {
            const float invT = 1.f / (Ti + EPSV);
            const float sc = ei / (ei * __expf(invT) + EPSV);
            cst[2 * t] = invT * 1.4426950408889634f;   // k1 (log2 exponent scale)
            cst[2 * t + 1] = __log2f(sc);              // lsc (folded post-scale)
        }
    }
}

// K1: fused 4-Gram MFMA + dual-tile persona epilogue over the upper triangle.
// 64x64 tile, 512 threads / 8 waves, each wave a 16x32 output slice:
// halves per-thread acc/epilogue state vs 4-wave version -> ~2x residency.
__global__ __launch_bounds__(512) void gram_kernel(
    const __hip_bfloat16* __restrict__ Abf, const __hip_bfloat16* __restrict__ Mbf,
    const float4* __restrict__ qtab, const float* __restrict__ cst,
    float* __restrict__ out) {
    // [0,32768): 2 buffers x 4 panels x [64][32] bf16 (reused for transpose).
    // [32768,37888): qrow (64 agents x 5 personas x float4)
    // [37888,43008): qcol
    __shared__ __align__(16) char smem[43008];

    const int t = threadIdx.x;
    const int lane = t & 63;
    const int w = t >> 6;          // 0..7
    const int wr = w >> 1;         // 0..3: 16-row strip
    const int wc = w & 1;          // 0..1: 32-col strip

    // XCD-chunked swizzle (2080 % 8 == 0 -> bijective): 260 consecutive tiles/XCD
    const int bid = ((int)blockIdx.x & 7) * 260 + ((int)blockIdx.x >> 3);
    int bx = (int)((sqrtf(8.f * (float)bid + 1.f) - 1.f) * 0.5f);
    while ((bx + 1) * (bx + 2) / 2 <= bid) ++bx;
    while (bx * (bx + 1) / 2 > bid) --bx;
    const int by = bid - bx * (bx + 1) / 2;
    const int row0 = by << 6, col0 = bx << 6;

    // ---- staging: wave w owns panel pn=w>>1 (0=rowA,1=rowM,2=colA,3=colM),
    // half hh=w&1 (32 rows); 2 gload16/thread/step. Source column pre-swizzled
    // (involution slot ^ ((row>>1)&3)); LDS stays linear.
    const int sslot = (lane & 3) ^ ((lane >> 3) & 3);
    const __hip_bfloat16* smat = ((w >> 1) & 1) ? Mbf : Abf;
    const int sbase = (w < 4) ? row0 : col0;
    const int hh = w & 1;
    const __hip_bfloat16* psrc =
        smat + (size_t)(sbase + hh * 32 + (lane >> 2)) * F + sslot * 8;
    const int ldsp = (w >> 1) * 4096 + hh * 2048;

    #define STAGE(b, ks)  do {                                            \
        const char* lb_ = smem + (b) * 16384 + ldsp;                      \
        gload16(psrc + (ks), lb_);                                        \
        gload16(psrc + (ks) + 16 * F, lb_ + 1024);                        \
    } while (0)

    // fragment-read geometry (matching swizzle)
    const int frow = lane & 15;
    const int fg = lane >> 4;
    const int jr = fg << 2;
    const int rdslot = (fg ^ ((frow >> 1) & 3)) << 4;
    const int aoff = (wr * 16 + frow) * 64 + rdslot;
    const int coff0 = (wc * 32 + frow) * 64 + rdslot;
    const int coff1 = (wc * 32 + 16 + frow) * 64 + rdslot;

    f32x4 acc[4][2];  // [gram AA,AM,MA,MM][n]
    #pragma unroll
    for (int g = 0; g < 4; ++g)
        #pragma unroll
        for (int n = 0; n < 2; ++n) acc[g][n] = (f32x4){0.f, 0.f, 0.f, 0.f};

    STAGE(0, 0);
    // qtab slices -> LDS (wave 0: row, wave 1: col); 5KB each, contiguous.
    if (w == 0) {
        #pragma unroll
        for (int it = 0; it < 5; ++it)
            gload16(qtab + row0 * P + it * 64 + lane, smem + 32768 + it * 1024);
    } else if (w == 1) {
        #pragma unroll
        for (int it = 0; it < 5; ++it)
            gload16(qtab + col0 * P + it * 64 + lane, smem + 37888 + it * 1024);
    }
    __syncthreads();

    for (int s = 0; s < NSTEP; ++s) {
        const int b = s & 1;
        if (s + 1 < NSTEP) STAGE(b ^ 1, (s + 1) * BK);
        const char* base = smem + b * 16384;
        const bf16x8 aA = *(const bf16x8*)(base + aoff);
        const bf16x8 aM = *(const bf16x8*)(base + 4096 + aoff);
        const bf16x8 bA0 = *(const bf16x8*)(base + 8192 + coff0);
        const bf16x8 bA1 = *(const bf16x8*)(base + 8192 + coff1);
        const bf16x8 bM0 = *(const bf16x8*)(base + 12288 + coff0);
        const bf16x8 bM1 = *(const bf16x8*)(base + 12288 + coff1);
        acc[0][0] = mfma16(aA, bA0, acc[0][0]);
        acc[0][1] = mfma16(aA, bA1, acc[0][1]);
        acc[1][0] = mfma16(aA, bM0, acc[1][0]);
        acc[1][1] = mfma16(aA, bM1, acc[1][1]);
        acc[2][0] = mfma16(aM, bA0, acc[2][0]);
        acc[2][1] = mfma16(aM, bA1, acc[2][1]);
        acc[3][0] = mfma16(aM, bM0, acc[3][0]);
        acc[3][1] = mfma16(aM, bM1, acc[3][1]);
        __syncthreads();
    }

    // Epilogue: g symmetric; out(r,c) = sum th*pc0*pr1, out(c,r) = sum th*pr0*pc1
    const float4* qrow = (const float4*)(smem + 32768);
    const float4* qcol = (const float4*)(smem + 37888);
    float o1[2][4], o2[2][4];  // [n][j]
    #pragma unroll
    for (int n = 0; n < 2; ++n)
        #pragma unroll
        for (int j = 0; j < 4; ++j) { o1[n][j] = 0.f; o2[n][j] = 0.f; }

    #pragma unroll
    for (int i = 0; i < P; ++i) {
        const float k1 = cst[2 * i], lsc = cst[2 * i + 1];
        float4 qc[2];
        #pragma unroll
        for (int n = 0; n < 2; ++n)
            qc[n] = qcol[(wc * 32 + n * 16 + frow) * P + i];
        #pragma unroll
        for (int j = 0; j < 4; ++j) {
            const float4 qr = qrow[(wr * 16 + jr + j) * P + i];
            #pragma unroll
            for (int n = 0; n < 2; ++n) {
                const float h0 = qr.x * acc[0][n][j] + qr.y * acc[2][n][j];
                const float h1 = qr.x * acc[1][n][j] + qr.y * acc[3][n][j];
                const float g = h0 * qc[n].x + h1 * qc[n].y;
                const float x = exp2f(fmaf(g, k1, lsc));
                const float e2 = exp2f(x * 2.8853900817779268f);  // exp(2x)
                const float th = 1.f - 2.f * __builtin_amdgcn_rcpf(e2 + 1.f);
                o1[n][j] = fmaf(th * qc[n].z, qr.w, o1[n][j]);
                o2[n][j] = fmaf(th * qr.z, qc[n].w, o2[n][j]);
            }
        }
    }

    // tile1 (row0, col0): direct coalesced stores
    #pragma unroll
    for (int j = 0; j < 4; ++j) {
        const int gr = row0 + wr * 16 + jr + j;
        #pragma unroll
        for (int n = 0; n < 2; ++n) {
            const int gc = col0 + wc * 32 + n * 16 + frow;
            out[(size_t)gr * N + gc] = o1[n][j];
        }
    }

    // tile2 (col0, row0): transpose through LDS (XOR-swizzled f32 [64][64] in
    // the panel area; panel reads finished before the final loop barrier),
    // then float4 stores
    if (by != bx) {
        float* tb = (float*)smem;
        #pragma unroll
        for (int n = 0; n < 2; ++n) {
            const int lc = wc * 32 + n * 16 + frow;
            #pragma unroll
            for (int j = 0; j < 4; ++j) {
                const int lr = wr * 16 + jr + j;
                tb[lc * 64 + (lr ^ ((lc & 15) << 2))] = o2[n][j];
            }
        }
        __syncthreads();
        const int trow = t >> 3;           // 0..63
        const int tc4 = (t & 7) << 2;      // 0,4,...,28
        #pragma unroll
        for (int k = 0; k < 2; ++k) {
            const int col = (tc4 + k * 32) ^ ((trow & 15) << 2);
            const float4 v = *(const float4*)&tb[trow * 64 + col];
            *(float4*)&out[(size_t)(col0 + trow) * N + row0 + tc4 + k * 32] = v;
        }
    }
    #undef STAGE
}

extern "C" void kernel_launch(void* const* d_in, const int* in_sizes, int n_in,
                              void* d_out, int out_size, void* d_ws, size_t ws_size,
                              hipStream_t stream) {
    const float* A = (const float*)d_in[0];
    const float* E = (const float*)d_in[1];
    const float* persona = (const float*)d_in[2];
    const float* T = (const float*)d_in[3];
    const float* e = (const float*)d_in[4];
    const float* r = (const float*)d_in[5];
    const float* W = (const float*)d_in[6];
    const int* times = (const int*)d_in[7];
    float* out = (float*)d_out;

    char* ws = (char*)d_ws;
    __hip_bfloat16* Abf = (__hip_bfloat16*)ws;                    // 2 MB
    __hip_bfloat16* Mbf = (__hip_bfloat16*)(ws + (2 << 20));      // 2 MB
    float4* qtab = (float4*)(ws + (4 << 20));                     // 320 KB
    float* cst = (float*)(ws + (4 << 20) + P * N * 16);           // 40 B

    prep_kernel<<<N, 256, 0, stream>>>(E, A, persona, T, e, r, W, times,
                                       Abf, Mbf, qtab, cst);
    const int ntri = 64 * 65 / 2;  // 2080 upper-triangle tiles
    gram_kernel<<<ntri, 512, 0, stream>>>(Abf, Mbf, qtab, cst, out);
}

// Round 9
// 101.561 us; speedup vs baseline: 1.4774x; 1.0261x over previous
//
#include <hip/hip_runtime.h>
#include <hip/hip_bf16.h>

#define N 4096
#define F 256
#define P 5
#define EPSV 1e-8f
#define BK 32
#define NSTEP (F / BK)  // 8
#define NTRI 2080       // 64*65/2 upper-triangle 64x64 tiles
#define GRIDSZ 512      // persistent blocks (2/CU x 256 CU)

typedef __attribute__((ext_vector_type(8))) short bf16x8;
typedef __attribute__((ext_vector_type(4))) float f32x4;

__device__ __forceinline__ f32x4 mfma16(bf16x8 a, bf16x8 b, f32x4 c) {
    return __builtin_amdgcn_mfma_f32_16x16x32_bf16(a, b, c, 0, 0, 0);
}

__device__ __forceinline__ void gload16(const void* src, const char* ldsdst) {
    __builtin_amdgcn_global_load_lds(
        (const __attribute__((address_space(1))) void*)src,
        (__attribute__((address_space(3))) void*)ldsdst, 16, 0, 0);
}

// K0 (fused): msg = E @ A via sparse index compaction, norms, bf16 casts,
// per-(agent,persona) float4 table {alpha, beta, p, p+delta} (AoS by agent),
// per-persona consts; also resets the gram work-stealing counter.
__global__ __launch_bounds__(256, 8) void prep_kernel(
    const float* __restrict__ E, const float* __restrict__ A,
    const float* __restrict__ persona,
    const float* __restrict__ Tt, const float* __restrict__ ee,
    const float* __restrict__ rr, const float* __restrict__ Ww,
    const int* __restrict__ times,
    __hip_bfloat16* __restrict__ Abf, __hip_bfloat16* __restrict__ Mbf,
    float4* __restrict__ qtab, float* __restrict__ cst, int* __restrict__ ctr) {
    __shared__ int cnt;
    __shared__ int list[1024];
    const int a = blockIdx.x;
    const int t = threadIdx.x;
    if (t == 0) cnt = 0;
    __syncthreads();
    const float4* erow = (const float4*)(E + (size_t)a * N);
    for (int b = t; b < N / 4; b += 256) {
        const float4 v = erow[b];
        if (v.x != 0.f) list[atomicAdd(&cnt, 1)] = 4 * b;
        if (v.y != 0.f) list[atomicAdd(&cnt, 1)] = 4 * b + 1;
        if (v.z != 0.f) list[atomicAdd(&cnt, 1)] = 4 * b + 2;
        if (v.w != 0.f) list[atomicAdd(&cnt, 1)] = 4 * b + 3;
    }
    __syncthreads();
    const int c = cnt;
    float s0 = 0.f, s1 = 0.f, s2 = 0.f, s3 = 0.f;
    float s4 = 0.f, s5 = 0.f, s6 = 0.f, s7 = 0.f;
    int j = 0;
    for (; j + 8 <= c; j += 8) {
        s0 += A[(size_t)list[j] * F + t];
        s1 += A[(size_t)list[j + 1] * F + t];
        s2 += A[(size_t)list[j + 2] * F + t];
        s3 += A[(size_t)list[j + 3] * F + t];
        s4 += A[(size_t)list[j + 4] * F + t];
        s5 += A[(size_t)list[j + 5] * F + t];
        s6 += A[(size_t)list[j + 6] * F + t];
        s7 += A[(size_t)list[j + 7] * F + t];
    }
    for (; j < c; ++j) s0 += A[(size_t)list[j] * F + t];
    const float mv = ((s0 + s1) + (s2 + s3)) + ((s4 + s5) + (s6 + s7));
    const float av = A[(size_t)a * F + t];
    Abf[(size_t)a * F + t] = __float2bfloat16(av);
    Mbf[(size_t)a * F + t] = __float2bfloat16(mv);

    float paa = av * av, pam = av * mv, pmm = mv * mv;
    #pragma unroll
    for (int o = 32; o > 0; o >>= 1) {
        paa += __shfl_down(paa, o);
        pam += __shfl_down(pam, o);
        pmm += __shfl_down(pmm, o);
    }
    __shared__ float s[3][4];
    const int wid = t >> 6;
    if ((t & 63) == 0) { s[0][wid] = paa; s[1][wid] = pam; s[2][wid] = pmm; }
    __syncthreads();
    if (t < P) {
        const float naa = s[0][0] + s[0][1] + s[0][2] + s[0][3];
        const float nam = s[1][0] + s[1][1] + s[1][2] + s[1][3];
        const float nmm = s[2][0] + s[2][1] + s[2][2] + s[2][3];
        const float Ti = Tt[t], ei = ee[t], ri = rr[t], Wi = Ww[t];
        const float wb = (1.f - ri) * Wi;
        const float n2 = ri * ri * naa + 2.f * ri * wb * nam + wb * wb * nmm;
        const float rn = rsqrtf(n2);
        const float p = persona[(size_t)(*times) * (size_t)N * P + (size_t)a * P + t];
        float4 q;
        q.x = ri * rn;                       // alpha
        q.y = wb * rn;                       // beta
        q.z = p;                             // p0
        q.w = p + (t == 0 ? 1.f : 0.f);      // p1 (i==0 init term)
        qtab[a * P + t] = q;                 // AoS by agent: personas contiguous
        if (a == 0) {
            const float invT = 1.f / (Ti + EPSV);
            const float sc = ei / (ei * __expf(invT) + EPSV);
            cst[2 * t] = invT * 1.4426950408889634f;   // k1 (log2 exponent scale)
            cst[2 * t + 1] = __log2f(sc);              // lsc (folded post-scale)
        }
    }
    if (a == 0 && t == 0) *ctr = GRIDSZ;  // work-stealing counter (stream-ordered)
}

// K1: persistent fused 4-Gram MFMA + dual-tile persona epilogue.
// 512 blocks x 8 waves; each block loops over stolen 64x64 triangle tiles.
// Wave = 16x32 output slice. Mirror tile stored directly (L2 write-merge).
__global__ __launch_bounds__(512) void gram_kernel(
    const __hip_bfloat16* __restrict__ Abf, const __hip_bfloat16* __restrict__ Mbf,
    const float4* __restrict__ qtab, const float* __restrict__ cst,
    int* __restrict__ ctr, float* __restrict__ out) {
    // [0,32768): 2 buffers x 4 panels x [64][32] bf16
    // [32768,37888): qrow (64 agents x 5 personas x float4); [37888,43008): qcol
    __shared__ __align__(16) char smem[43008];
    __shared__ int snext;

    const int t = threadIdx.x;
    const int lane = t & 63;
    const int w = t >> 6;          // 0..7
    const int wr = w >> 1;         // 0..3: 16-row strip
    const int wc = w & 1;          // 0..1: 32-col strip

    // staging geometry: wave w owns panel pn=w>>1 (0=rowA,1=rowM,2=colA,3=colM),
    // half hh=w&1; source column pre-swizzled (involution slot^((row>>1)&3)).
    const int sslot = (lane & 3) ^ ((lane >> 3) & 3);
    const int srowoff = (w & 1) * 32 + (lane >> 2);
    const int ldsp = (w >> 1) * 4096 + (w & 1) * 2048;
    const __hip_bfloat16* smat = ((w >> 1) & 1) ? Mbf : Abf;

    // fragment-read geometry (matching swizzle)
    const int frow = lane & 15;
    const int fg = lane >> 4;
    const int jr = fg << 2;
    const int rdslot = (fg ^ ((frow >> 1) & 3)) << 4;
    const int aoff = (wr * 16 + frow) * 64 + rdslot;
    const int coff0 = (wc * 32 + frow) * 64 + rdslot;
    const int coff1 = (wc * 32 + 16 + frow) * 64 + rdslot;

    const float4* qrow = (const float4*)(smem + 32768);
    const float4* qcol = (const float4*)(smem + 37888);

    int raw = blockIdx.x;
    while (raw < NTRI) {
        // XCD-chunked bijective swizzle (2080 % 8 == 0)
        const int bid = (raw & 7) * 260 + (raw >> 3);
        int bx = (int)((sqrtf(8.f * (float)bid + 1.f) - 1.f) * 0.5f);
        while ((bx + 1) * (bx + 2) / 2 <= bid) ++bx;
        while (bx * (bx + 1) / 2 > bid) --bx;
        const int by = bid - bx * (bx + 1) / 2;
        const int row0 = by << 6, col0 = bx << 6;

        const int sbase = (w < 4) ? row0 : col0;
        const __hip_bfloat16* psrc =
            smat + (size_t)(sbase + srowoff) * F + sslot * 8;

        #define STAGE(b, ks)  do {                                        \
            const char* lb_ = smem + (b) * 16384 + ldsp;                  \
            gload16(psrc + (ks), lb_);                                    \
            gload16(psrc + (ks) + 16 * F, lb_ + 1024);                    \
        } while (0)

        __syncthreads();  // all LDS reads of previous tile complete
        STAGE(0, 0);
        if (w == 0) {
            #pragma unroll
            for (int it = 0; it < 5; ++it)
                gload16(qtab + row0 * P + it * 64 + lane, smem + 32768 + it * 1024);
        } else if (w == 1) {
            #pragma unroll
            for (int it = 0; it < 5; ++it)
                gload16(qtab + col0 * P + it * 64 + lane, smem + 37888 + it * 1024);
        }
        if (t == 0) snext = atomicAdd(ctr, 1);
        __syncthreads();

        f32x4 acc[4][2];  // [gram AA,AM,MA,MM][n]
        #pragma unroll
        for (int g = 0; g < 4; ++g)
            #pragma unroll
            for (int n = 0; n < 2; ++n) acc[g][n] = (f32x4){0.f, 0.f, 0.f, 0.f};

        for (int s = 0; s < NSTEP; ++s) {
            const int b = s & 1;
            if (s + 1 < NSTEP) STAGE(b ^ 1, (s + 1) * BK);
            const char* base = smem + b * 16384;
            const bf16x8 aA = *(const bf16x8*)(base + aoff);
            const bf16x8 aM = *(const bf16x8*)(base + 4096 + aoff);
            const bf16x8 bA0 = *(const bf16x8*)(base + 8192 + coff0);
            const bf16x8 bA1 = *(const bf16x8*)(base + 8192 + coff1);
            const bf16x8 bM0 = *(const bf16x8*)(base + 12288 + coff0);
            const bf16x8 bM1 = *(const bf16x8*)(base + 12288 + coff1);
            acc[0][0] = mfma16(aA, bA0, acc[0][0]);
            acc[0][1] = mfma16(aA, bA1, acc[0][1]);
            acc[1][0] = mfma16(aA, bM0, acc[1][0]);
            acc[1][1] = mfma16(aA, bM1, acc[1][1]);
            acc[2][0] = mfma16(aM, bA0, acc[2][0]);
            acc[2][1] = mfma16(aM, bA1, acc[2][1]);
            acc[3][0] = mfma16(aM, bM0, acc[3][0]);
            acc[3][1] = mfma16(aM, bM1, acc[3][1]);
            if (s + 1 < NSTEP) __syncthreads();
            // no barrier after last step: epilogue only reads qtab LDS; panel
            // overwrite is behind the next tile's leading __syncthreads.
        }

        // Epilogue: g symmetric; out(r,c)=sum th*pc0*pr1, out(c,r)=sum th*pr0*pc1
        float o1[2][4], o2[2][4];  // [n][j]
        #pragma unroll
        for (int n = 0; n < 2; ++n)
            #pragma unroll
            for (int j = 0; j < 4; ++j) { o1[n][j] = 0.f; o2[n][j] = 0.f; }

        #pragma unroll
        for (int i = 0; i < P; ++i) {
            const float k1 = cst[2 * i], lsc = cst[2 * i + 1];
            float4 qc[2];
            #pragma unroll
            for (int n = 0; n < 2; ++n)
                qc[n] = qcol[(wc * 32 + n * 16 + frow) * P + i];
            #pragma unroll
            for (int j = 0; j < 4; ++j) {
                const float4 qr = qrow[(wr * 16 + jr + j) * P + i];
                #pragma unroll
                for (int n = 0; n < 2; ++n) {
                    const float h0 = qr.x * acc[0][n][j] + qr.y * acc[2][n][j];
                    const float h1 = qr.x * acc[1][n][j] + qr.y * acc[3][n][j];
                    const float g = h0 * qc[n].x + h1 * qc[n].y;
                    const float x = exp2f(fmaf(g, k1, lsc));
                    const float e2 = exp2f(x * 2.8853900817779268f);  // exp(2x)
                    const float th = 1.f - 2.f * __builtin_amdgcn_rcpf(e2 + 1.f);
                    o1[n][j] = fmaf(th * qc[n].z, qr.w, o1[n][j]);
                    o2[n][j] = fmaf(th * qr.z, qc[n].w, o2[n][j]);
                }
            }
        }

        // tile1 (row0, col0): coalesced stores (16 lanes x 4B per row segment)
        #pragma unroll
        for (int j = 0; j < 4; ++j) {
            const int gr = row0 + wr * 16 + jr + j;
            #pragma unroll
            for (int n = 0; n < 2; ++n) {
                const int gc = col0 + wc * 32 + n * 16 + frow;
                out[(size_t)gr * N + gc] = o1[n][j];
            }
        }
        // tile2 (col0, row0): direct transposed scalar stores (L2 write-merged;
        // round-5 evidence: WRITE_SIZE stays at the 64MB ideal)
        if (by != bx) {
            #pragma unroll
            for (int j = 0; j < 4; ++j) {
                const int gr = row0 + wr * 16 + jr + j;
                #pragma unroll
                for (int n = 0; n < 2; ++n) {
                    const int gc = col0 + wc * 32 + n * 16 + frow;
                    out[(size_t)gc * N + gr] = o2[n][j];
                }
            }
        }
        raw = snext;  // uniform; next write is behind two barriers
        #undef STAGE
    }
}

extern "C" void kernel_launch(void* const* d_in, const int* in_sizes, int n_in,
                              void* d_out, int out_size, void* d_ws, size_t ws_size,
                              hipStream_t stream) {
    const float* A = (const float*)d_in[0];
    const float* E = (const float*)d_in[1];
    const float* persona = (const float*)d_in[2];
    const float* T = (const float*)d_in[3];
    const float* e = (const float*)d_in[4];
    const float* r = (const float*)d_in[5];
    const float* W = (const float*)d_in[6];
    const int* times = (const int*)d_in[7];
    float* out = (float*)d_out;

    char* ws = (char*)d_ws;
    __hip_bfloat16* Abf = (__hip_bfloat16*)ws;                    // 2 MB
    __hip_bfloat16* Mbf = (__hip_bfloat16*)(ws + (2 << 20));      // 2 MB
    float4* qtab = (float4*)(ws + (4 << 20));                     // 320 KB
    float* cst = (float*)(ws + (4 << 20) + P * N * 16);           // 40 B
    int* ctr = (int*)(ws + (4 << 20) + P * N * 16 + 64);          // 4 B

    prep_kernel<<<N, 256, 0, stream>>>(E, A, persona, T, e, r, W, times,
                                       Abf, Mbf, qtab, cst, ctr);
    gram_kernel<<<GRIDSZ, 512, 0, stream>>>(Abf, Mbf, qtab, cst, ctr, out);
}